// Round 1
// baseline (4164.640 us; speedup 1.0000x reference)
//
#include <hip/hip_runtime.h>
#include <hip/hip_bf16.h>

#define HEADS   16
#define KV_LORA 512
#define S_LEN   2048
#define BATCH   2
#define MTOT    (BATCH * S_LEN)   // 4096
#define HIDDEN  2048
#define SCALE   0.125f

// ---------------------------------------------------------------------------
// Tiled fp32 GEMM: C[M x N] = A[M x K] @ W[K x N]
// 128x128 tile, BK=16, 256 threads, 8x8 micro-tile/thread.
// M, K assumed multiples of 128/16 (true for all call sites). N guarded.
// ---------------------------------------------------------------------------
__global__ __launch_bounds__(256)
void gemm_f32(const float* __restrict__ A, int lda,
              const float* __restrict__ W, int N, int K,
              float* __restrict__ C, int ldc)
{
    __shared__ float As[16][132];   // [k][row], pad 132 -> 2-way max on stores
    __shared__ float Bs[16][132];   // [k][col]

    const int t  = threadIdx.x;
    const int tx = t & 15;          // output col group
    const int ty = t >> 4;          // output row group
    const int row0 = blockIdx.y * 128;
    const int col0 = blockIdx.x * 128;

    float acc[8][8];
#pragma unroll
    for (int i = 0; i < 8; i++)
#pragma unroll
        for (int j = 0; j < 8; j++) acc[i][j] = 0.f;

    for (int k0 = 0; k0 < K; k0 += 16) {
        __syncthreads();
        // stage A tile (128 rows x 16 k) transposed into As[k][row]
#pragma unroll
        for (int ii = 0; ii < 2; ii++) {
            int fa = t + 256 * ii;            // float4 index, 0..511
            int ar = fa >> 2;                 // row in tile 0..127
            int ac = (fa & 3) << 2;           // k offset 0,4,8,12
            float4 v = *(const float4*)&A[(size_t)(row0 + ar) * lda + k0 + ac];
            As[ac + 0][ar] = v.x; As[ac + 1][ar] = v.y;
            As[ac + 2][ar] = v.z; As[ac + 3][ar] = v.w;
            // stage B tile (16 k x 128 cols)
            int bk = fa >> 5;                 // 0..15
            int bc = (fa & 31) << 2;          // 0..124
            float4 w = make_float4(0.f, 0.f, 0.f, 0.f);
            if (col0 + bc < N)
                w = *(const float4*)&W[(size_t)(k0 + bk) * N + col0 + bc];
            *(float4*)&Bs[bk][bc] = w;
        }
        __syncthreads();
#pragma unroll
        for (int kk = 0; kk < 16; kk++) {
            float4 a0 = *(const float4*)&As[kk][ty * 8];
            float4 a1 = *(const float4*)&As[kk][ty * 8 + 4];
            float4 b0 = *(const float4*)&Bs[kk][tx * 8];
            float4 b1 = *(const float4*)&Bs[kk][tx * 8 + 4];
            float av[8] = {a0.x, a0.y, a0.z, a0.w, a1.x, a1.y, a1.z, a1.w};
            float bv[8] = {b0.x, b0.y, b0.z, b0.w, b1.x, b1.y, b1.z, b1.w};
#pragma unroll
            for (int i = 0; i < 8; i++)
#pragma unroll
                for (int j = 0; j < 8; j++)
                    acc[i][j] += av[i] * bv[j];
        }
    }

#pragma unroll
    for (int i = 0; i < 8; i++) {
        int r = row0 + ty * 8 + i;
        int c = col0 + tx * 8;
        if (c < N) {
            float4 o0 = {acc[i][0], acc[i][1], acc[i][2], acc[i][3]};
            *(float4*)&C[(size_t)r * ldc + c] = o0;
        }
        if (c + 4 < N) {
            float4 o1 = {acc[i][4], acc[i][5], acc[i][6], acc[i][7]};
            *(float4*)&C[(size_t)r * ldc + c + 4] = o1;
        }
    }
}

// ---------------------------------------------------------------------------
// Flash-style MLA attention, fp32.
// Block: 256 threads handles 16 q-rows for one (b,h). K-tiles of 64 keys.
// k_full[d] = d<64 ? k_rope (head-shared, kv_down col 512+d)
//                  : k_nope (kv col h*192 + d-64);  v = kv col h*192+64+d.
// Thread t: q-row i = t>>4, score cols j = (t&15)*4..+3, ctx dims d0=(t&15)*8..+7.
// ---------------------------------------------------------------------------
__global__ __launch_bounds__(256)
void mla_attn(const float* __restrict__ kvdown,  // [MTOT][576]
              const float* __restrict__ kvup,    // [MTOT][3072]
              const float* __restrict__ qbuf,    // [MTOT][2048] (rope|nope per head)
              const float* __restrict__ mask,    // [S][S]
              float* __restrict__ ctx)           // [MTOT][2048]
{
    __shared__ float Kt[128][68];   // transposed: Kt[d][j], pad 68
    __shared__ float Vf[64][128];   // Vf[j][d]
    __shared__ float Qf[16][132];   // Qf[i][d], pad 132
    __shared__ float Pl[16][65];    // probs, pad 65

    const int t  = threadIdx.x;
    const int qi = t >> 4;          // 0..15
    const int g  = t & 15;
    const int d0 = g * 8;
    const int b  = blockIdx.z, h = blockIdx.y;
    const int q0 = blockIdx.x * 16;
    const size_t base = (size_t)b * S_LEN;

    // stage Q tile
#pragma unroll
    for (int ii = 0; ii < 2; ii++) {
        int f = t + 256 * ii;
        int r = f >> 5, c4 = (f & 31) << 2;
        float4 v = *(const float4*)&qbuf[(base + q0 + r) * 2048 + h * 128 + c4];
        *(float4*)&Qf[r][c4] = v;
    }

    float m = -INFINITY, l = 0.f;
    float acc[8];
#pragma unroll
    for (int u = 0; u < 8; u++) acc[u] = 0.f;

    for (int kt = 0; kt < S_LEN / 64; kt++) {
        const int s0 = kt * 64;
        __syncthreads();   // previous tile fully consumed
        // stage K (transposed) and V
#pragma unroll
        for (int ii = 0; ii < 8; ii++) {
            int f = t + 256 * ii;
            int r = f >> 5, c4 = (f & 31) << 2;   // r 0..63, c4 0..124
            size_t rowb = base + s0 + r;
            float4 kvv;
            if (c4 < 64) kvv = *(const float4*)&kvdown[rowb * 576 + 512 + c4];
            else         kvv = *(const float4*)&kvup[rowb * 3072 + h * 192 + (c4 - 64)];
            Kt[c4 + 0][r] = kvv.x; Kt[c4 + 1][r] = kvv.y;
            Kt[c4 + 2][r] = kvv.z; Kt[c4 + 3][r] = kvv.w;
            float4 vv = *(const float4*)&kvup[rowb * 3072 + h * 192 + 64 + c4];
            *(float4*)&Vf[r][c4] = vv;
        }
        __syncthreads();

        // scores: 4 j's per thread, vectorized over j via transposed Kt
        float sc0 = 0.f, sc1 = 0.f, sc2 = 0.f, sc3 = 0.f;
#pragma unroll 8
        for (int d4 = 0; d4 < 32; d4++) {
            float4 qv4 = *(const float4*)&Qf[qi][d4 * 4];
            float qa[4] = {qv4.x, qv4.y, qv4.z, qv4.w};
#pragma unroll
            for (int dd = 0; dd < 4; dd++) {
                float4 k4 = *(const float4*)&Kt[d4 * 4 + dd][g * 4];
                sc0 += qa[dd] * k4.x; sc1 += qa[dd] * k4.y;
                sc2 += qa[dd] * k4.z; sc3 += qa[dd] * k4.w;
            }
        }
        const float* mrow = &mask[(size_t)(q0 + qi) * S_LEN + s0 + g * 4];
        sc0 = sc0 * SCALE + mrow[0];
        sc1 = sc1 * SCALE + mrow[1];
        sc2 = sc2 * SCALE + mrow[2];
        sc3 = sc3 * SCALE + mrow[3];

        // online softmax over the 16 threads sharing row qi
        float tm = fmaxf(fmaxf(sc0, sc1), fmaxf(sc2, sc3));
#pragma unroll
        for (int off = 1; off < 16; off <<= 1) tm = fmaxf(tm, __shfl_xor(tm, off));
        float mnew = fmaxf(m, tm);
        float sold = __expf(m - mnew);
        float p0 = __expf(sc0 - mnew), p1 = __expf(sc1 - mnew);
        float p2 = __expf(sc2 - mnew), p3 = __expf(sc3 - mnew);
        float ps = p0 + p1 + p2 + p3;
#pragma unroll
        for (int off = 1; off < 16; off <<= 1) ps += __shfl_xor(ps, off);
        l = l * sold + ps;
        m = mnew;
#pragma unroll
        for (int u = 0; u < 8; u++) acc[u] *= sold;
        Pl[qi][g * 4 + 0] = p0; Pl[qi][g * 4 + 1] = p1;
        Pl[qi][g * 4 + 2] = p2; Pl[qi][g * 4 + 3] = p3;
        __syncthreads();

        // ctx accumulation: acc[d0..d0+7] += sum_j P[qi][j] * V[j][d]
#pragma unroll 8
        for (int j = 0; j < 64; j++) {
            float p = Pl[qi][j];
            float4 v0 = *(const float4*)&Vf[j][d0];
            float4 v1 = *(const float4*)&Vf[j][d0 + 4];
            acc[0] += p * v0.x; acc[1] += p * v0.y;
            acc[2] += p * v0.z; acc[3] += p * v0.w;
            acc[4] += p * v1.x; acc[5] += p * v1.y;
            acc[6] += p * v1.z; acc[7] += p * v1.w;
        }
    }

    float inv = 1.0f / l;
    float4 o0 = {acc[0] * inv, acc[1] * inv, acc[2] * inv, acc[3] * inv};
    float4 o1 = {acc[4] * inv, acc[5] * inv, acc[6] * inv, acc[7] * inv};
    float* dst = &ctx[(base + q0 + qi) * 2048 + h * 128 + d0];
    *(float4*)&dst[0] = o0;
    *(float4*)&dst[4] = o1;
}

// ---------------------------------------------------------------------------
extern "C" void kernel_launch(void* const* d_in, const int* in_sizes, int n_in,
                              void* d_out, int out_size, void* d_ws, size_t ws_size,
                              hipStream_t stream)
{
    const float* hidden = (const float*)d_in[0];
    const float* mask   = (const float*)d_in[1];
    const float* W_down = (const float*)d_in[2];
    const float* W_up   = (const float*)d_in[3];
    const float* W_q    = (const float*)d_in[4];
    const float* W_o    = (const float*)d_in[5];
    float* out = (float*)d_out;

    float* ws     = (float*)d_ws;
    float* kvdown = ws;                                   // 4096 x 576
    float* kvup   = kvdown + (size_t)MTOT * 576;          // 4096 x 3072
    float* qbuf   = kvup   + (size_t)MTOT * 3072;         // 4096 x 2048
    float* ctxb   = qbuf   + (size_t)MTOT * 2048;         // 4096 x 2048

    dim3 blk(256);
    // kv_down = hidden @ W_down  (N=576)
    gemm_f32<<<dim3((576 + 127) / 128, MTOT / 128), blk, 0, stream>>>(
        hidden, HIDDEN, W_down, 576, HIDDEN, kvdown, 576);
    // q = hidden @ W_q  (N=2048)
    gemm_f32<<<dim3(2048 / 128, MTOT / 128), blk, 0, stream>>>(
        hidden, HIDDEN, W_q, 2048, HIDDEN, qbuf, 2048);
    // kv = kv_compressed @ W_up  (A = kvdown cols 0..511, lda=576; N=3072)
    gemm_f32<<<dim3(3072 / 128, MTOT / 128), blk, 0, stream>>>(
        kvdown, 576, W_up, 3072, KV_LORA, kvup, 3072);
    // attention -> ctx
    mla_attn<<<dim3(S_LEN / 16, HEADS, BATCH), blk, 0, stream>>>(
        kvdown, kvup, qbuf, mask, ctxb);
    // out = ctx @ W_o  (N=2048)
    gemm_f32<<<dim3(2048 / 128, MTOT / 128), blk, 0, stream>>>(
        ctxb, 2048, W_o, 2048, HIDDEN, out, 2048);
}

// Round 2
// 388.446 us; speedup vs baseline: 10.7213x; 10.7213x over previous
//
#include <hip/hip_runtime.h>
#include <hip/hip_bf16.h>

#define HEADS   16
#define S_LEN   2048
#define BATCH   2
#define MTOT    (BATCH * S_LEN)   // 4096
#define HIDDEN  2048
#define SCALE   0.125f

typedef __attribute__((ext_vector_type(8))) short          bf16x8;
typedef __attribute__((ext_vector_type(8))) unsigned short u16x8;
typedef __attribute__((ext_vector_type(4))) float          f32x4;

__device__ __forceinline__ unsigned short f2bf(float f) {
    union { float f; unsigned u; } v; v.f = f;
    unsigned r = v.u + 0x7FFFu + ((v.u >> 16) & 1u);
    return (unsigned short)(r >> 16);
}

__device__ __forceinline__ void gld16(const void* g, const void* l) {
    __builtin_amdgcn_global_load_lds(
        (const __attribute__((address_space(1))) void*)g,
        (__attribute__((address_space(3))) void*)l, 16, 0, 0);
}

// ---------------------------------------------------------------------------
// elementwise f32 -> bf16 cast (8 elems/thread)
// ---------------------------------------------------------------------------
__global__ __launch_bounds__(256)
void cast_bf16(const float* __restrict__ in, unsigned short* __restrict__ out)
{
    const size_t i = ((size_t)blockIdx.x * 256 + threadIdx.x) * 8;
    float4 a = *(const float4*)&in[i];
    float4 b = *(const float4*)&in[i + 4];
    u16x8 o;
    o[0] = f2bf(a.x); o[1] = f2bf(a.y); o[2] = f2bf(a.z); o[3] = f2bf(a.w);
    o[4] = f2bf(b.x); o[5] = f2bf(b.y); o[6] = f2bf(b.z); o[7] = f2bf(b.w);
    *(u16x8*)&out[i] = o;
}

// ---------------------------------------------------------------------------
// transpose + cast weights: W f32 [K][N] -> Wt bf16 [Npad][K]
// grid = (Npad/64, K/64); tiles with n0 >= N write zeros.
// ---------------------------------------------------------------------------
__global__ __launch_bounds__(256)
void tc_w(const float* __restrict__ W, int N, int K, unsigned short* __restrict__ Wt)
{
    __shared__ float Tf[64][68];
    const int t  = threadIdx.x;
    const int n0 = blockIdx.x * 64, k0 = blockIdx.y * 64;
    if (n0 >= N) {
        u16x8 z = {0,0,0,0,0,0,0,0};
#pragma unroll
        for (int ii = 0; ii < 2; ii++) {
            int idx = t + 256 * ii;
            int rn = idx >> 3, c8 = (idx & 7) * 8;
            *(u16x8*)&Wt[(size_t)(n0 + rn) * K + k0 + c8] = z;
        }
        return;
    }
#pragma unroll
    for (int ii = 0; ii < 4; ii++) {
        int idx = t + 256 * ii;
        int rk = idx >> 4, c4 = (idx & 15) * 4;
        *(float4*)&Tf[rk][c4] = *(const float4*)&W[(size_t)(k0 + rk) * N + n0 + c4];
    }
    __syncthreads();
#pragma unroll
    for (int ii = 0; ii < 2; ii++) {
        int idx = t + 256 * ii;
        int rn = idx >> 3, c8 = (idx & 7) * 8;
        u16x8 o;
#pragma unroll
        for (int j = 0; j < 8; j++) o[j] = f2bf(Tf[c8 + j][rn]);
        *(u16x8*)&Wt[(size_t)(n0 + rn) * K + k0 + c8] = o;
    }
}

// ---------------------------------------------------------------------------
// V transpose: kvu bf16 [MTOT][3072] (v = cols h*192+64..191) -> vT [B*H*128][S]
// ---------------------------------------------------------------------------
__global__ __launch_bounds__(256)
void transpose_v(const unsigned short* __restrict__ kvu, unsigned short* __restrict__ vT)
{
    __shared__ unsigned short Ts[64][80];
    const int t  = threadIdx.x;
    const int s0 = blockIdx.x * 64;
    const int h  = blockIdx.y >> 1, d0 = (blockIdx.y & 1) * 64;
    const int b  = blockIdx.z;
    const size_t base = (size_t)b * S_LEN;
#pragma unroll
    for (int ii = 0; ii < 2; ii++) {
        int idx = t + 256 * ii;
        int rs = idx >> 3, c8 = (idx & 7) * 8;
        *(u16x8*)&Ts[rs][c8] =
            *(const u16x8*)&kvu[(base + s0 + rs) * 3072 + h * 192 + 64 + d0 + c8];
    }
    __syncthreads();
    const size_t bh = (size_t)(b * HEADS + h);
#pragma unroll
    for (int ii = 0; ii < 2; ii++) {
        int idx = t + 256 * ii;
        int rd = idx >> 3, c8 = (idx & 7) * 8;
        u16x8 o;
#pragma unroll
        for (int j = 0; j < 8; j++) o[j] = Ts[c8 + j][rd];
        *(u16x8*)&vT[(bh * 128 + d0 + rd) * S_LEN + s0 + c8] = o;
    }
}

// ---------------------------------------------------------------------------
// bf16 MFMA GEMM (m97 structure): C[M x N] = A[M x K] @ Bt[N x K]^T
// 128x128 tile, BK=32, 4 waves, global_load_lds staging, 16x16x32 bf16 MFMA.
// ---------------------------------------------------------------------------
template<bool OUT_BF16>
__global__ __launch_bounds__(256)
void gemm_bf16(const unsigned short* __restrict__ A, int lda, int K,
               const unsigned short* __restrict__ Bt,
               void* __restrict__ C, int N, int ldc)
{
    __shared__ unsigned short As[128 * 32];
    __shared__ unsigned short Bs[128 * 32];
    const int t = threadIdx.x, lane = t & 63, w = t >> 6;
    const int l15 = lane & 15, lg = lane >> 4;
    const int row0 = blockIdx.y * 128, col0 = blockIdx.x * 128;
    const int wr = w >> 1, wc = w & 1;

    f32x4 acc[4][4] = {};

    for (int k0 = 0; k0 < K; k0 += 32) {
        __syncthreads();
#pragma unroll
        for (int ii = 0; ii < 2; ii++) {
            int u = (ii * 4 + w) * 64 + lane;
            gld16(&A[(size_t)(row0 + (u >> 2)) * lda + k0 + (u & 3) * 8],
                  (char*)As + (ii * 4 + w) * 1024);
            gld16(&Bt[(size_t)(col0 + (u >> 2)) * K + k0 + (u & 3) * 8],
                  (char*)Bs + (ii * 4 + w) * 1024);
        }
        __syncthreads();
        bf16x8 af[4], bb[4];
#pragma unroll
        for (int m = 0; m < 4; m++)
            af[m] = *(const bf16x8*)&As[(wr * 64 + m * 16 + l15) * 32 + lg * 8];
#pragma unroll
        for (int n = 0; n < 4; n++)
            bb[n] = *(const bf16x8*)&Bs[(wc * 64 + n * 16 + l15) * 32 + lg * 8];
#pragma unroll
        for (int m = 0; m < 4; m++)
#pragma unroll
            for (int n = 0; n < 4; n++)
                acc[m][n] = __builtin_amdgcn_mfma_f32_16x16x32_bf16(
                    af[m], bb[n], acc[m][n], 0, 0, 0);
    }

#pragma unroll
    for (int m = 0; m < 4; m++)
#pragma unroll
        for (int n = 0; n < 4; n++) {
            int col = col0 + wc * 64 + n * 16 + l15;
            if (col < N) {
#pragma unroll
                for (int r = 0; r < 4; r++) {
                    int row = row0 + wr * 64 + m * 16 + lg * 4 + r;
                    if (OUT_BF16)
                        ((unsigned short*)C)[(size_t)row * ldc + col] = f2bf(acc[m][n][r]);
                    else
                        ((float*)C)[(size_t)row * ldc + col] = acc[m][n][r];
                }
            }
        }
}

// ---------------------------------------------------------------------------
// MFMA flash attention. Block = 4 waves; wave w owns 16 q-rows.
// K-tile 64 keys x 128 d staged swizzled (rope from kvd, nope from kvu);
// V-tile from pre-transposed vT. Online softmax; P re-laid out via wave-local LDS.
// ---------------------------------------------------------------------------
__global__ __launch_bounds__(256)
void mla_attn_mfma(const unsigned short* __restrict__ kvd,   // [MTOT][576]
                   const unsigned short* __restrict__ kvu,   // [MTOT][3072]
                   const unsigned short* __restrict__ qb,    // [MTOT][2048]
                   const unsigned short* __restrict__ vT,    // [B*H*128][S]
                   const float* __restrict__ mask,           // [S][S]
                   unsigned short* __restrict__ ctxb)        // [MTOT][2048]
{
    __shared__ unsigned short Ks[64 * 128];   // [key][d], chunks XOR-swizzled
    __shared__ unsigned short Vs[128 * 64];   // [d][key], chunks XOR-swizzled
    __shared__ unsigned short Pl[4 * 16 * 88];
    const int t = threadIdx.x, lane = t & 63, w = t >> 6;
    const int l15 = lane & 15, lg = lane >> 4;
    const int h = blockIdx.y, b = blockIdx.z;
    const int q0 = blockIdx.x * 64 + w * 16;
    const size_t base = (size_t)b * S_LEN;
    const size_t bh = (size_t)(b * HEADS + h);
    unsigned short* Pw = &Pl[w * 16 * 88];

    bf16x8 qf[4];
#pragma unroll
    for (int kk = 0; kk < 4; kk++)
        qf[kk] = *(const bf16x8*)&qb[(base + q0 + l15) * 2048 + h * 128 + kk * 32 + lg * 8];

    f32x4 octx[8] = {};
    float mrun[4], lrun[4];
#pragma unroll
    for (int r = 0; r < 4; r++) { mrun[r] = -INFINITY; lrun[r] = 0.f; }

    for (int kt = 0; kt < S_LEN / 64; kt++) {
        const int s0 = kt * 64;
        __syncthreads();
        // ---- stage K (rope|nope) and V, pre-swizzled global source ----
#pragma unroll
        for (int ii = 0; ii < 4; ii++) {
            int u = (ii * 4 + w) * 64 + lane;
            { // K: row=key (0..63), 16 chunks of 8 bf16
                int row = u >> 4, x = u & 15, y = x ^ (row & 7);
                const unsigned short* g = (y < 8)
                    ? &kvd[(base + s0 + row) * 576 + 512 + y * 8]
                    : &kvu[(base + s0 + row) * 3072 + h * 192 + (y - 8) * 8];
                gld16(g, (char*)Ks + (ii * 4 + w) * 1024);
            }
            { // V: row=d (0..127), 8 chunks of 8 bf16
                int d = u >> 3, x = u & 7, y = x ^ (d & 7);
                gld16(&vT[(bh * 128 + d) * S_LEN + s0 + y * 8],
                      (char*)Vs + (ii * 4 + w) * 1024);
            }
        }
        __syncthreads();

        // ---- scores S[q][key] ----
        f32x4 sc[4] = {};
#pragma unroll
        for (int n = 0; n < 4; n++) {
            int key = n * 16 + l15;
#pragma unroll
            for (int kk = 0; kk < 4; kk++) {
                int x = (kk * 4 + lg) ^ (key & 7);
                bf16x8 kf = *(const bf16x8*)&Ks[key * 128 + x * 8];
                sc[n] = __builtin_amdgcn_mfma_f32_16x16x32_bf16(qf[kk], kf, sc[n], 0, 0, 0);
            }
        }

        // ---- online softmax (rows q = lg*4 + r) ----
        float esc[4];
#pragma unroll
        for (int r = 0; r < 4; r++) {
            const size_t qg = (size_t)(q0 + lg * 4 + r);
            float sv[4];
#pragma unroll
            for (int n = 0; n < 4; n++)
                sv[n] = sc[n][r] * SCALE + mask[qg * S_LEN + s0 + n * 16 + l15];
            float mx = fmaxf(fmaxf(sv[0], sv[1]), fmaxf(sv[2], sv[3]));
#pragma unroll
            for (int off = 1; off < 16; off <<= 1) mx = fmaxf(mx, __shfl_xor(mx, off));
            float mnew = fmaxf(mrun[r], mx);
            esc[r] = __expf(mrun[r] - mnew);
            mrun[r] = mnew;
            float ps = 0.f;
#pragma unroll
            for (int n = 0; n < 4; n++) {
                float p = __expf(sv[n] - mnew);
                ps += p;
                Pw[(lg * 4 + r) * 88 + n * 16 + l15] = f2bf(p);
            }
#pragma unroll
            for (int off = 1; off < 16; off <<= 1) ps += __shfl_xor(ps, off);
            lrun[r] = lrun[r] * esc[r] + ps;
        }
#pragma unroll
        for (int vn = 0; vn < 8; vn++) {
#pragma unroll
            for (int r = 0; r < 4; r++) octx[vn][r] *= esc[r];
        }

        // ---- PV ----
        bf16x8 pf[2];
#pragma unroll
        for (int kk = 0; kk < 2; kk++)
            pf[kk] = *(const bf16x8*)&Pw[l15 * 88 + kk * 32 + lg * 8];
#pragma unroll
        for (int vn = 0; vn < 8; vn++) {
            int d = vn * 16 + l15;
#pragma unroll
            for (int kk = 0; kk < 2; kk++) {
                int x = (kk * 4 + lg) ^ (d & 7);
                bf16x8 vf = *(const bf16x8*)&Vs[d * 64 + x * 8];
                octx[vn] = __builtin_amdgcn_mfma_f32_16x16x32_bf16(pf[kk], vf, octx[vn], 0, 0, 0);
            }
        }
    }

#pragma unroll
    for (int r = 0; r < 4; r++) {
        float inv = 1.0f / lrun[r];
        size_t row = base + q0 + lg * 4 + r;
#pragma unroll
        for (int vn = 0; vn < 8; vn++)
            ctxb[row * 2048 + h * 128 + vn * 16 + l15] = f2bf(octx[vn][r] * inv);
    }
}

// ---------------------------------------------------------------------------
extern "C" void kernel_launch(void* const* d_in, const int* in_sizes, int n_in,
                              void* d_out, int out_size, void* d_ws, size_t ws_size,
                              hipStream_t stream)
{
    const float* hidden = (const float*)d_in[0];
    const float* mask   = (const float*)d_in[1];
    const float* W_down = (const float*)d_in[2];
    const float* W_up   = (const float*)d_in[3];
    const float* W_q    = (const float*)d_in[4];
    const float* W_o    = (const float*)d_in[5];
    float* out = (float*)d_out;

    unsigned short* p = (unsigned short*)d_ws;
    unsigned short* hb      = p; p += (size_t)MTOT * 2048;   // bf16 hidden
    unsigned short* kvd_b   = p; p += (size_t)MTOT * 576;
    unsigned short* kvu_b   = p; p += (size_t)MTOT * 3072;
    unsigned short* qb      = p; p += (size_t)MTOT * 2048;
    unsigned short* vTb     = p; p += (size_t)BATCH * HEADS * 128 * S_LEN;
    unsigned short* ctxb    = p; p += (size_t)MTOT * 2048;
    unsigned short* Wt_down = p; p += (size_t)640 * 2048;
    unsigned short* Wt_up   = p; p += (size_t)3072 * 512;
    unsigned short* Wt_q    = p; p += (size_t)2048 * 2048;
    unsigned short* Wt_o    = p; p += (size_t)2048 * 2048;

    dim3 blk(256);
    cast_bf16<<<dim3(MTOT * 2048 / (256 * 8)), blk, 0, stream>>>(hidden, hb);
    tc_w<<<dim3(10, 32), blk, 0, stream>>>(W_down, 576, 2048, Wt_down);
    tc_w<<<dim3(48, 8),  blk, 0, stream>>>(W_up, 3072, 512, Wt_up);
    tc_w<<<dim3(32, 32), blk, 0, stream>>>(W_q, 2048, 2048, Wt_q);
    tc_w<<<dim3(32, 32), blk, 0, stream>>>(W_o, 2048, 2048, Wt_o);

    gemm_bf16<true><<<dim3(5, 32), blk, 0, stream>>>(hb, 2048, 2048, Wt_down, kvd_b, 576, 576);
    gemm_bf16<true><<<dim3(24, 32), blk, 0, stream>>>(kvd_b, 576, 512, Wt_up, kvu_b, 3072, 3072);
    gemm_bf16<true><<<dim3(16, 32), blk, 0, stream>>>(hb, 2048, 2048, Wt_q, qb, 2048, 2048);

    transpose_v<<<dim3(S_LEN / 64, 2 * HEADS, BATCH), blk, 0, stream>>>(kvu_b, vTb);

    mla_attn_mfma<<<dim3(S_LEN / 64, HEADS, BATCH), blk, 0, stream>>>(
        kvd_b, kvu_b, qb, vTb, mask, ctxb);

    gemm_bf16<false><<<dim3(16, 32), blk, 0, stream>>>(ctxb, 2048, 2048, Wt_o, out, 2048, 2048);
}

// Round 4
// 302.517 us; speedup vs baseline: 13.7666x; 1.2840x over previous
//
#include <hip/hip_runtime.h>
#include <hip/hip_bf16.h>

#define HEADS   16
#define S_LEN   2048
#define BATCH   2
#define MTOT    (BATCH * S_LEN)   // 4096
#define HIDDEN  2048
#define SCALE   0.125f
#define QKD_LD  2688              // fused (kv_down | q) output row stride

typedef __attribute__((ext_vector_type(8))) short          bf16x8;
typedef __attribute__((ext_vector_type(8))) unsigned short u16x8;
typedef __attribute__((ext_vector_type(4))) unsigned short u16x4;
typedef __attribute__((ext_vector_type(4))) float          f32x4;

__device__ __forceinline__ unsigned short f2bf(float f) {
    union { float f; unsigned u; } v; v.f = f;
    unsigned r = v.u + 0x7FFFu + ((v.u >> 16) & 1u);
    return (unsigned short)(r >> 16);
}

__device__ __forceinline__ void gld16(const void* g, const void* l) {
    __builtin_amdgcn_global_load_lds(
        (const __attribute__((address_space(1))) void*)g,
        (__attribute__((address_space(3))) void*)l, 16, 0, 0);
}

// ---------------------------------------------------------------------------
// elementwise f32 -> bf16 cast (8 elems/thread)
// ---------------------------------------------------------------------------
__global__ __launch_bounds__(256)
void cast_bf16(const float* __restrict__ in, unsigned short* __restrict__ out)
{
    const size_t i = ((size_t)blockIdx.x * 256 + threadIdx.x) * 8;
    float4 a = *(const float4*)&in[i];
    float4 b = *(const float4*)&in[i + 4];
    u16x8 o;
    o[0] = f2bf(a.x); o[1] = f2bf(a.y); o[2] = f2bf(a.z); o[3] = f2bf(a.w);
    o[4] = f2bf(b.x); o[5] = f2bf(b.y); o[6] = f2bf(b.z); o[7] = f2bf(b.w);
    *(u16x8*)&out[i] = o;
}

// ---------------------------------------------------------------------------
// transpose + cast weights: W f32 [K][N] -> Wt bf16 [Npad][K]
// ---------------------------------------------------------------------------
__global__ __launch_bounds__(256)
void tc_w(const float* __restrict__ W, int N, int K, unsigned short* __restrict__ Wt)
{
    __shared__ float Tf[64][68];
    const int t  = threadIdx.x;
    const int n0 = blockIdx.x * 64, k0 = blockIdx.y * 64;
    if (n0 >= N) {
        u16x8 z = {0,0,0,0,0,0,0,0};
#pragma unroll
        for (int ii = 0; ii < 2; ii++) {
            int idx = t + 256 * ii;
            int rn = idx >> 3, c8 = (idx & 7) * 8;
            *(u16x8*)&Wt[(size_t)(n0 + rn) * K + k0 + c8] = z;
        }
        return;
    }
#pragma unroll
    for (int ii = 0; ii < 4; ii++) {
        int idx = t + 256 * ii;
        int rk = idx >> 4, c4 = (idx & 15) * 4;
        *(float4*)&Tf[rk][c4] = *(const float4*)&W[(size_t)(k0 + rk) * N + n0 + c4];
    }
    __syncthreads();
#pragma unroll
    for (int ii = 0; ii < 2; ii++) {
        int idx = t + 256 * ii;
        int rn = idx >> 3, c8 = (idx & 7) * 8;
        u16x8 o;
#pragma unroll
        for (int j = 0; j < 8; j++) o[j] = f2bf(Tf[c8 + j][rn]);
        *(u16x8*)&Wt[(size_t)(n0 + rn) * K + k0 + c8] = o;
    }
}

// ---------------------------------------------------------------------------
// V transpose: kvu bf16 [MTOT][3072] (v = cols h*192+64..191) -> vT [B*H*128][S]
// ---------------------------------------------------------------------------
__global__ __launch_bounds__(256)
void transpose_v(const unsigned short* __restrict__ kvu, unsigned short* __restrict__ vT)
{
    __shared__ unsigned short Ts[64][80];
    const int t  = threadIdx.x;
    const int s0 = blockIdx.x * 64;
    const int h  = blockIdx.y >> 1, d0 = (blockIdx.y & 1) * 64;
    const int b  = blockIdx.z;
    const size_t base = (size_t)b * S_LEN;
#pragma unroll
    for (int ii = 0; ii < 2; ii++) {
        int idx = t + 256 * ii;
        int rs = idx >> 3, c8 = (idx & 7) * 8;
        *(u16x8*)&Ts[rs][c8] =
            *(const u16x8*)&kvu[(base + s0 + rs) * 3072 + h * 192 + 64 + d0 + c8];
    }
    __syncthreads();
    const size_t bh = (size_t)(b * HEADS + h);
#pragma unroll
    for (int ii = 0; ii < 2; ii++) {
        int idx = t + 256 * ii;
        int rd = idx >> 3, c8 = (idx & 7) * 8;
        u16x8 o;
#pragma unroll
        for (int j = 0; j < 8; j++) o[j] = Ts[c8 + j][rd];
        *(u16x8*)&vT[(bh * 128 + d0 + rd) * S_LEN + s0 + c8] = o;
    }
}

// ---------------------------------------------------------------------------
// bf16 MFMA GEMM (m97 structure): C[M x N] = A[M x K] @ Bt[N x K]^T
// ---------------------------------------------------------------------------
template<bool OUT_BF16>
__global__ __launch_bounds__(256)
void gemm_bf16(const unsigned short* __restrict__ A, int lda, int K,
               const unsigned short* __restrict__ Bt,
               void* __restrict__ C, int N, int ldc)
{
    __shared__ unsigned short As[128 * 32];
    __shared__ unsigned short Bs[128 * 32];
    const int t = threadIdx.x, lane = t & 63, w = t >> 6;
    const int l15 = lane & 15, lg = lane >> 4;
    const int row0 = blockIdx.y * 128, col0 = blockIdx.x * 128;
    const int wr = w >> 1, wc = w & 1;

    f32x4 acc[4][4] = {};

    for (int k0 = 0; k0 < K; k0 += 32) {
        __syncthreads();
#pragma unroll
        for (int ii = 0; ii < 2; ii++) {
            int u = (ii * 4 + w) * 64 + lane;
            gld16(&A[(size_t)(row0 + (u >> 2)) * lda + k0 + (u & 3) * 8],
                  (char*)As + (ii * 4 + w) * 1024);
            gld16(&Bt[(size_t)(col0 + (u >> 2)) * K + k0 + (u & 3) * 8],
                  (char*)Bs + (ii * 4 + w) * 1024);
        }
        __syncthreads();
        bf16x8 af[4], bb[4];
#pragma unroll
        for (int m = 0; m < 4; m++)
            af[m] = *(const bf16x8*)&As[(wr * 64 + m * 16 + l15) * 32 + lg * 8];
#pragma unroll
        for (int n = 0; n < 4; n++)
            bb[n] = *(const bf16x8*)&Bs[(wc * 64 + n * 16 + l15) * 32 + lg * 8];
#pragma unroll
        for (int m = 0; m < 4; m++)
#pragma unroll
            for (int n = 0; n < 4; n++)
                acc[m][n] = __builtin_amdgcn_mfma_f32_16x16x32_bf16(
                    af[m], bb[n], acc[m][n], 0, 0, 0);
    }

#pragma unroll
    for (int m = 0; m < 4; m++)
#pragma unroll
        for (int n = 0; n < 4; n++) {
            int col = col0 + wc * 64 + n * 16 + l15;
            if (col < N) {
#pragma unroll
                for (int r = 0; r < 4; r++) {
                    int row = row0 + wr * 64 + m * 16 + lg * 4 + r;
                    if (OUT_BF16)
                        ((unsigned short*)C)[(size_t)row * ldc + col] = f2bf(acc[m][n][r]);
                    else
                        ((float*)C)[(size_t)row * ldc + col] = acc[m][n][r];
                }
            }
        }
}

// ---------------------------------------------------------------------------
// MFMA flash attention, swapped-QK^T layout.
// Block = 4 waves x 32 q-rows = 128 q-rows per (b,h). K-tiles of 64 keys.
// sc[m][n][r] = S[key = n*16+lg*4+r][q = q0+m*16+l15]. Mask reads float4;
// row softmax lane-local + shfl_xor(16,32). P stored to wave-local LDS as
// SHORT-typed vectors (TBAA-safe vs the short-vector PV reads) with an
// explicit compiler memory fence before the PV fragment loads.
// ---------------------------------------------------------------------------
__global__ __launch_bounds__(256, 2)
void mla_attn_mfma(const unsigned short* __restrict__ qkd,   // [MTOT][2688]: rope at col 512, q at 640
                   const unsigned short* __restrict__ kvu,   // [MTOT][3072]
                   const unsigned short* __restrict__ vT,    // [B*H*128][S]
                   const float* __restrict__ mask,           // [S][S]
                   unsigned short* __restrict__ ctxb)        // [MTOT][2048]
{
    __shared__ unsigned short Ks[64 * 128];   // [key][d], chunks XOR-swizzled
    __shared__ unsigned short Vs[128 * 64];   // [d][key], chunks XOR-swizzled
    __shared__ unsigned short Pl[4][32 * 72]; // per-wave P, pitch 72
    const int t = threadIdx.x, lane = t & 63, w = t >> 6;
    const int l15 = lane & 15, lg = lane >> 4;
    const int h = blockIdx.y, b = blockIdx.z;
    const int q0 = blockIdx.x * 128 + w * 32;   // this wave's 32 q-rows
    const size_t base = (size_t)b * S_LEN;
    const size_t bh = (size_t)(b * HEADS + h);
    const unsigned short* qb = qkd + 640;
    unsigned short* Pw = &Pl[w][0];

    // Q fragments (B-operand): lane holds q-col (m*16+l15), k-dims lg*8 per kk
    bf16x8 qf[2][4];
#pragma unroll
    for (int m = 0; m < 2; m++)
#pragma unroll
        for (int kk = 0; kk < 4; kk++)
            qf[m][kk] = *(const bf16x8*)&qb[(base + q0 + m * 16 + l15) * QKD_LD
                                            + h * 128 + kk * 32 + lg * 8];

    f32x4 octx[2][8] = {};
    float mrun[2] = {-INFINITY, -INFINITY};
    float lrun[2] = {0.f, 0.f};

    for (int kt = 0; kt < S_LEN / 64; kt++) {
        const int s0 = kt * 64;
        __syncthreads();
        // ---- stage K (rope|nope) and V, pre-swizzled global source ----
#pragma unroll
        for (int ii = 0; ii < 4; ii++) {
            int u = (ii * 4 + w) * 64 + lane;
            { // K: row=key (0..63), 16 chunks of 8 bf16
                int row = u >> 4, x = u & 15, y = x ^ (row & 7);
                const unsigned short* g = (y < 8)
                    ? &qkd[(base + s0 + row) * QKD_LD + 512 + y * 8]
                    : &kvu[(base + s0 + row) * 3072 + h * 192 + (y - 8) * 8];
                gld16(g, (char*)Ks + (ii * 4 + w) * 1024);
            }
            { // V: row=d (0..127), 8 chunks of 8 bf16
                int d = u >> 3, x = u & 7, y = x ^ (d & 7);
                gld16(&vT[(bh * 128 + d) * S_LEN + s0 + y * 8],
                      (char*)Vs + (ii * 4 + w) * 1024);
            }
        }
        __syncthreads();

        // ---- scores S[key][q]: sc[m][n][r] = S[n*16+lg*4+r][m*16+l15] ----
        f32x4 sc[2][4] = {};
#pragma unroll
        for (int n = 0; n < 4; n++) {
            const int key = n * 16 + l15;
#pragma unroll
            for (int kk = 0; kk < 4; kk++) {
                const int x = (kk * 4 + lg) ^ (key & 7);
                bf16x8 kf = *(const bf16x8*)&Ks[key * 128 + x * 8];
                sc[0][n] = __builtin_amdgcn_mfma_f32_16x16x32_bf16(kf, qf[0][kk], sc[0][n], 0, 0, 0);
                sc[1][n] = __builtin_amdgcn_mfma_f32_16x16x32_bf16(kf, qf[1][kk], sc[1][n], 0, 0, 0);
            }
        }

        // ---- online softmax per q-row (lane-local row = l15, per m) ----
        float e_bc[2][4];
#pragma unroll
        for (int m = 0; m < 2; m++) {
            const size_t qrow = (size_t)(q0 + m * 16 + l15);
            float sv[4][4];
#pragma unroll
            for (int n = 0; n < 4; n++) {
                float4 mv = *(const float4*)&mask[qrow * S_LEN + s0 + n * 16 + lg * 4];
                sv[n][0] = sc[m][n][0] * SCALE + mv.x;
                sv[n][1] = sc[m][n][1] * SCALE + mv.y;
                sv[n][2] = sc[m][n][2] * SCALE + mv.z;
                sv[n][3] = sc[m][n][3] * SCALE + mv.w;
            }
            float loc = sv[0][0];
#pragma unroll
            for (int n = 0; n < 4; n++)
#pragma unroll
                for (int r = 0; r < 4; r++) loc = fmaxf(loc, sv[n][r]);
            loc = fmaxf(loc, __shfl_xor(loc, 16));
            loc = fmaxf(loc, __shfl_xor(loc, 32));
            float mnew = fmaxf(mrun[m], loc);
            float esc = __expf(mrun[m] - mnew);
            mrun[m] = mnew;
            float ls = 0.f;
#pragma unroll
            for (int n = 0; n < 4; n++) {
                float p0 = __expf(sv[n][0] - mnew), p1 = __expf(sv[n][1] - mnew);
                float p2 = __expf(sv[n][2] - mnew), p3 = __expf(sv[n][3] - mnew);
                ls += (p0 + p1) + (p2 + p3);
                u16x4 pk = { f2bf(p0), f2bf(p1), f2bf(p2), f2bf(p3) };
                *(u16x4*)&Pw[(m * 16 + l15) * 72 + n * 16 + lg * 4] = pk;
            }
            ls += __shfl_xor(ls, 16);
            ls += __shfl_xor(ls, 32);
            lrun[m] = lrun[m] * esc + ls;
#pragma unroll
            for (int r = 0; r < 4; r++) e_bc[m][r] = __shfl(esc, lg * 4 + r);
        }

        // ---- rescale ctx ----
#pragma unroll
        for (int m = 0; m < 2; m++)
#pragma unroll
            for (int vn = 0; vn < 8; vn++)
#pragma unroll
                for (int r = 0; r < 4; r++) octx[m][vn][r] *= e_bc[m][r];

        // compiler memory fence: P stores must not be reordered past PV loads
        asm volatile("" ::: "memory");

        // ---- PV ----
        bf16x8 paf[2][2];
#pragma unroll
        for (int m = 0; m < 2; m++)
#pragma unroll
            for (int kk = 0; kk < 2; kk++)
                paf[m][kk] = *(const bf16x8*)&Pw[(m * 16 + l15) * 72 + kk * 32 + lg * 8];
#pragma unroll
        for (int vn = 0; vn < 8; vn++) {
            const int d = vn * 16 + l15;
#pragma unroll
            for (int kk = 0; kk < 2; kk++) {
                const int x = (kk * 4 + lg) ^ (d & 7);
                bf16x8 vf = *(const bf16x8*)&Vs[d * 64 + x * 8];
                octx[0][vn] = __builtin_amdgcn_mfma_f32_16x16x32_bf16(paf[0][kk], vf, octx[0][vn], 0, 0, 0);
                octx[1][vn] = __builtin_amdgcn_mfma_f32_16x16x32_bf16(paf[1][kk], vf, octx[1][vn], 0, 0, 0);
            }
        }
    }

    // ---- normalize + write ----
#pragma unroll
    for (int m = 0; m < 2; m++) {
        float inv[4];
#pragma unroll
        for (int r = 0; r < 4; r++) inv[r] = 1.0f / __shfl(lrun[m], lg * 4 + r);
#pragma unroll
        for (int vn = 0; vn < 8; vn++)
#pragma unroll
            for (int r = 0; r < 4; r++)
                ctxb[(base + q0 + m * 16 + lg * 4 + r) * 2048 + h * 128 + vn * 16 + l15]
                    = f2bf(octx[m][vn][r] * inv[r]);
    }
}

// ---------------------------------------------------------------------------
extern "C" void kernel_launch(void* const* d_in, const int* in_sizes, int n_in,
                              void* d_out, int out_size, void* d_ws, size_t ws_size,
                              hipStream_t stream)
{
    const float* hidden = (const float*)d_in[0];
    const float* mask   = (const float*)d_in[1];
    const float* W_down = (const float*)d_in[2];
    const float* W_up   = (const float*)d_in[3];
    const float* W_q    = (const float*)d_in[4];
    const float* W_o    = (const float*)d_in[5];
    float* out = (float*)d_out;

    unsigned short* p = (unsigned short*)d_ws;
    unsigned short* hb      = p; p += (size_t)MTOT * 2048;     // bf16 hidden
    unsigned short* qkd     = p; p += (size_t)MTOT * QKD_LD;   // kv_down(640) | q(2048)
    unsigned short* kvu_b   = p; p += (size_t)MTOT * 3072;
    unsigned short* vTb     = p; p += (size_t)BATCH * HEADS * 128 * S_LEN;
    unsigned short* ctxb    = p; p += (size_t)MTOT * 2048;
    unsigned short* Wt_cat  = p; p += (size_t)QKD_LD * 2048;   // W_down^T (640) | W_q^T (2048)
    unsigned short* Wt_up   = p; p += (size_t)3072 * 512;
    unsigned short* Wt_o    = p; p += (size_t)2048 * 2048;

    dim3 blk(256);
    cast_bf16<<<dim3(MTOT * 2048 / (256 * 8)), blk, 0, stream>>>(hidden, hb);
    tc_w<<<dim3(10, 32), blk, 0, stream>>>(W_down, 576, 2048, Wt_cat);
    tc_w<<<dim3(32, 32), blk, 0, stream>>>(W_q, 2048, 2048, Wt_cat + (size_t)640 * 2048);
    tc_w<<<dim3(48, 8),  blk, 0, stream>>>(W_up, 3072, 512, Wt_up);
    tc_w<<<dim3(32, 32), blk, 0, stream>>>(W_o, 2048, 2048, Wt_o);

    // fused (kv_down | q) = hb @ Wt_cat^T
    gemm_bf16<true><<<dim3(QKD_LD / 128, 32), blk, 0, stream>>>(
        hb, 2048, 2048, Wt_cat, qkd, QKD_LD, QKD_LD);
    // kv = kv_compressed @ W_up  (A = qkd cols 0..511, lda=2688)
    gemm_bf16<true><<<dim3(24, 32), blk, 0, stream>>>(
        qkd, QKD_LD, 512, Wt_up, kvu_b, 3072, 3072);

    transpose_v<<<dim3(S_LEN / 64, 2 * HEADS, BATCH), blk, 0, stream>>>(kvu_b, vTb);

    mla_attn_mfma<<<dim3(S_LEN / 128, HEADS, BATCH), blk, 0, stream>>>(
        qkd, kvu_b, vTb, mask, ctxb);

    gemm_bf16<false><<<dim3(16, 32), blk, 0, stream>>>(
        ctxb, 2048, 2048, Wt_o, out, 2048, 2048);
}

// Round 5
// 297.546 us; speedup vs baseline: 13.9966x; 1.0167x over previous
//
#include <hip/hip_runtime.h>
#include <hip/hip_bf16.h>

#define HEADS   16
#define S_LEN   2048
#define BATCH   2
#define MTOT    (BATCH * S_LEN)   // 4096
#define HIDDEN  2048
#define SCALE   0.125f
#define QKD_LD  2688              // fused (kv_down | q) output row stride

typedef __attribute__((ext_vector_type(8))) short          bf16x8;
typedef __attribute__((ext_vector_type(8))) unsigned short u16x8;
typedef __attribute__((ext_vector_type(4))) unsigned short u16x4;
typedef __attribute__((ext_vector_type(4))) float          f32x4;

__device__ __forceinline__ unsigned short f2bf(float f) {
    union { float f; unsigned u; } v; v.f = f;
    unsigned r = v.u + 0x7FFFu + ((v.u >> 16) & 1u);
    return (unsigned short)(r >> 16);
}

// packed f32x2 -> bf16x2 (RTNE): D.lo = bf16(a), D.hi = bf16(b)
__device__ __forceinline__ unsigned cvtpk(float a, float b) {
    unsigned r;
    asm("v_cvt_pk_bf16_f32 %0, %1, %2" : "=v"(r) : "v"(a), "v"(b));
    return r;
}

__device__ __forceinline__ void gld16(const void* g, const void* l) {
    __builtin_amdgcn_global_load_lds(
        (const __attribute__((address_space(1))) void*)g,
        (__attribute__((address_space(3))) void*)l, 16, 0, 0);
}

// ---------------------------------------------------------------------------
// elementwise f32 -> bf16 cast (8 elems/thread)
// ---------------------------------------------------------------------------
__global__ __launch_bounds__(256)
void cast_bf16(const float* __restrict__ in, unsigned short* __restrict__ out)
{
    const size_t i = ((size_t)blockIdx.x * 256 + threadIdx.x) * 8;
    float4 a = *(const float4*)&in[i];
    float4 b = *(const float4*)&in[i + 4];
    u16x8 o;
    o[0] = f2bf(a.x); o[1] = f2bf(a.y); o[2] = f2bf(a.z); o[3] = f2bf(a.w);
    o[4] = f2bf(b.x); o[5] = f2bf(b.y); o[6] = f2bf(b.z); o[7] = f2bf(b.w);
    *(u16x8*)&out[i] = o;
}

// ---------------------------------------------------------------------------
// transpose + cast weights: W f32 [K][N] -> Wt bf16 [Npad][K]
// ---------------------------------------------------------------------------
__global__ __launch_bounds__(256)
void tc_w(const float* __restrict__ W, int N, int K, unsigned short* __restrict__ Wt)
{
    __shared__ float Tf[64][68];
    const int t  = threadIdx.x;
    const int n0 = blockIdx.x * 64, k0 = blockIdx.y * 64;
    if (n0 >= N) {
        u16x8 z = {0,0,0,0,0,0,0,0};
#pragma unroll
        for (int ii = 0; ii < 2; ii++) {
            int idx = t + 256 * ii;
            int rn = idx >> 3, c8 = (idx & 7) * 8;
            *(u16x8*)&Wt[(size_t)(n0 + rn) * K + k0 + c8] = z;
        }
        return;
    }
#pragma unroll
    for (int ii = 0; ii < 4; ii++) {
        int idx = t + 256 * ii;
        int rk = idx >> 4, c4 = (idx & 15) * 4;
        *(float4*)&Tf[rk][c4] = *(const float4*)&W[(size_t)(k0 + rk) * N + n0 + c4];
    }
    __syncthreads();
#pragma unroll
    for (int ii = 0; ii < 2; ii++) {
        int idx = t + 256 * ii;
        int rn = idx >> 3, c8 = (idx & 7) * 8;
        u16x8 o;
#pragma unroll
        for (int j = 0; j < 8; j++) o[j] = f2bf(Tf[c8 + j][rn]);
        *(u16x8*)&Wt[(size_t)(n0 + rn) * K + k0 + c8] = o;
    }
}

// ---------------------------------------------------------------------------
// V transpose: kvu bf16 [MTOT][3072] (v = cols h*192+64..191) -> vT [B*H*128][S]
// ---------------------------------------------------------------------------
__global__ __launch_bounds__(256)
void transpose_v(const unsigned short* __restrict__ kvu, unsigned short* __restrict__ vT)
{
    __shared__ unsigned short Ts[64][80];
    const int t  = threadIdx.x;
    const int s0 = blockIdx.x * 64;
    const int h  = blockIdx.y >> 1, d0 = (blockIdx.y & 1) * 64;
    const int b  = blockIdx.z;
    const size_t base = (size_t)b * S_LEN;
#pragma unroll
    for (int ii = 0; ii < 2; ii++) {
        int idx = t + 256 * ii;
        int rs = idx >> 3, c8 = (idx & 7) * 8;
        *(u16x8*)&Ts[rs][c8] =
            *(const u16x8*)&kvu[(base + s0 + rs) * 3072 + h * 192 + 64 + d0 + c8];
    }
    __syncthreads();
    const size_t bh = (size_t)(b * HEADS + h);
#pragma unroll
    for (int ii = 0; ii < 2; ii++) {
        int idx = t + 256 * ii;
        int rd = idx >> 3, c8 = (idx & 7) * 8;
        u16x8 o;
#pragma unroll
        for (int j = 0; j < 8; j++) o[j] = Ts[c8 + j][rd];
        *(u16x8*)&vT[(bh * 128 + d0 + rd) * S_LEN + s0 + c8] = o;
    }
}

// ---------------------------------------------------------------------------
// bf16 MFMA GEMM (m97 structure): C[M x N] = A[M x K] @ Bt[N x K]^T
// ---------------------------------------------------------------------------
template<bool OUT_BF16>
__global__ __launch_bounds__(256)
void gemm_bf16(const unsigned short* __restrict__ A, int lda, int K,
               const unsigned short* __restrict__ Bt,
               void* __restrict__ C, int N, int ldc)
{
    __shared__ unsigned short As[128 * 32];
    __shared__ unsigned short Bs[128 * 32];
    const int t = threadIdx.x, lane = t & 63, w = t >> 6;
    const int l15 = lane & 15, lg = lane >> 4;
    const int row0 = blockIdx.y * 128, col0 = blockIdx.x * 128;
    const int wr = w >> 1, wc = w & 1;

    f32x4 acc[4][4] = {};

    for (int k0 = 0; k0 < K; k0 += 32) {
        __syncthreads();
#pragma unroll
        for (int ii = 0; ii < 2; ii++) {
            int u = (ii * 4 + w) * 64 + lane;
            gld16(&A[(size_t)(row0 + (u >> 2)) * lda + k0 + (u & 3) * 8],
                  (char*)As + (ii * 4 + w) * 1024);
            gld16(&Bt[(size_t)(col0 + (u >> 2)) * K + k0 + (u & 3) * 8],
                  (char*)Bs + (ii * 4 + w) * 1024);
        }
        __syncthreads();
        bf16x8 af[4], bb[4];
#pragma unroll
        for (int m = 0; m < 4; m++)
            af[m] = *(const bf16x8*)&As[(wr * 64 + m * 16 + l15) * 32 + lg * 8];
#pragma unroll
        for (int n = 0; n < 4; n++)
            bb[n] = *(const bf16x8*)&Bs[(wc * 64 + n * 16 + l15) * 32 + lg * 8];
#pragma unroll
        for (int m = 0; m < 4; m++)
#pragma unroll
            for (int n = 0; n < 4; n++)
                acc[m][n] = __builtin_amdgcn_mfma_f32_16x16x32_bf16(
                    af[m], bb[n], acc[m][n], 0, 0, 0);
    }

#pragma unroll
    for (int m = 0; m < 4; m++)
#pragma unroll
        for (int n = 0; n < 4; n++) {
            int col = col0 + wc * 64 + n * 16 + l15;
            if (col < N) {
#pragma unroll
                for (int r = 0; r < 4; r++) {
                    int row = row0 + wr * 64 + m * 16 + lg * 4 + r;
                    if (OUT_BF16)
                        ((unsigned short*)C)[(size_t)row * ldc + col] = f2bf(acc[m][n][r]);
                    else
                        ((float*)C)[(size_t)row * ldc + col] = acc[m][n][r];
                }
            }
        }
}

// ---------------------------------------------------------------------------
// MFMA flash attention, swapped-QK^T, 2-phase prefetch pipeline.
// Block = 4 waves x 32 q-rows = 128 q-rows per (b,h). K-tiles of 64 keys,
// K+V double-buffered in LDS. Per tile: raw barrier -> issue mask loads ->
// issue next-tile stage (8 gld16) -> s_waitcnt vmcnt(16) (drains own current
// stage, keeps mask+prefetch in flight) -> raw barrier -> QK/softmax/PV.
// P tile is XOR-swizzled wave-local LDS (pitch 64).
// ---------------------------------------------------------------------------
__global__ __launch_bounds__(256, 2)
void mla_attn_mfma(const unsigned short* __restrict__ qkd,   // [MTOT][2688]: rope at 512, q at 640
                   const unsigned short* __restrict__ kvu,   // [MTOT][3072]
                   const unsigned short* __restrict__ vT,    // [B*H*128][S]
                   const float* __restrict__ mask,           // [S][S]
                   unsigned short* __restrict__ ctxb)        // [MTOT][2048]
{
    __shared__ unsigned short KV[2][64 * 128 + 128 * 64];  // [buf]{K,V}, 32KB each
    __shared__ unsigned short Pl[4][32 * 64];              // per-wave P, swizzled
    const int t = threadIdx.x, lane = t & 63, w = t >> 6;
    const int l15 = lane & 15, lg = lane >> 4;
    const int h = blockIdx.y, b = blockIdx.z;
    const int q0 = blockIdx.x * 128 + w * 32;   // this wave's 32 q-rows
    const size_t base = (size_t)b * S_LEN;
    const size_t bh = (size_t)(b * HEADS + h);
    const unsigned short* qb = qkd + 640;
    unsigned short* Pw = &Pl[w][0];
    const unsigned psw = (unsigned)(l15 & 7) << 4;  // P swizzle

    // Q fragments (B-operand): lane holds q-col (m*16+l15), k-dims lg*8 per kk
    bf16x8 qf[2][4];
#pragma unroll
    for (int m = 0; m < 2; m++)
#pragma unroll
        for (int kk = 0; kk < 4; kk++)
            qf[m][kk] = *(const bf16x8*)&qb[(base + q0 + m * 16 + l15) * QKD_LD
                                            + h * 128 + kk * 32 + lg * 8];

    f32x4 octx[2][8] = {};
    float mrun[2] = {-INFINITY, -INFINITY};
    float lrun[2] = {0.f, 0.f};

    const float* mrow0 = &mask[(size_t)(q0 + l15) * S_LEN + lg * 4];
    const float* mrow1 = mrow0 + (size_t)16 * S_LEN;

    // ---- stage helper: 8 gld16 into KV[buf] ----
    auto STAGE = [&](int buf, int s0) {
        unsigned short* Kb = &KV[buf][0];
        unsigned short* Vb = &KV[buf][64 * 128];
#pragma unroll
        for (int ii = 0; ii < 4; ii++) {
            int u = (ii * 4 + w) * 64 + lane;
            { // K: row=key (0..63), 16 chunks of 8 bf16, rope|nope
                int row = u >> 4, x = u & 15, y = x ^ (row & 7);
                const unsigned short* g = (y < 8)
                    ? &qkd[(base + s0 + row) * QKD_LD + 512 + y * 8]
                    : &kvu[(base + s0 + row) * 3072 + h * 192 + (y - 8) * 8];
                gld16(g, (char*)Kb + (ii * 4 + w) * 1024);
            }
            { // V: row=d (0..127), 8 chunks of 8 bf16
                int d = u >> 3, x = u & 7, y = x ^ (d & 7);
                gld16(&vT[(bh * 128 + d) * S_LEN + s0 + y * 8],
                      (char*)Vb + (ii * 4 + w) * 1024);
            }
        }
    };

    const int NT = S_LEN / 64;
    STAGE(0, 0);   // prologue: tile 0 into buf 0

    for (int kt = 0; kt < NT; kt++) {
        const int cur = kt & 1;
        const int s0 = kt * 64;
        const unsigned short* Ks = &KV[cur][0];
        const unsigned short* Vs = &KV[cur][64 * 128];

        // barrier 1: all waves done with PV(kt-1) -> buf[cur^1] is free
        __builtin_amdgcn_s_barrier();

        // issue mask(kt) loads (before stage, so its use-wait won't drain prefetch)
        float4 mv[2][4];
#pragma unroll
        for (int n = 0; n < 4; n++) {
            mv[0][n] = *(const float4*)&mrow0[s0 + n * 16];
            mv[1][n] = *(const float4*)&mrow1[s0 + n * 16];
        }
        __builtin_amdgcn_sched_barrier(0);

        // issue stage(kt+1) into buf^1
        if (kt + 1 < NT) {
            STAGE(cur ^ 1, s0 + 64);
            __builtin_amdgcn_sched_barrier(0);
            asm volatile("s_waitcnt vmcnt(16)" ::: "memory");  // drain own stage(kt)
        } else {
            __builtin_amdgcn_sched_barrier(0);
            asm volatile("s_waitcnt vmcnt(8)" ::: "memory");   // only mask younger
        }
        __builtin_amdgcn_sched_barrier(0);
        // barrier 2: all waves' stage(kt) complete -> buf[cur] valid
        __builtin_amdgcn_s_barrier();

        // ---- scores S[key][q]: sc[m][n][r] = S[n*16+lg*4+r][m*16+l15] ----
        f32x4 sc[2][4] = {};
        __builtin_amdgcn_s_setprio(1);
#pragma unroll
        for (int n = 0; n < 4; n++) {
            const int key = n * 16 + l15;
#pragma unroll
            for (int kk = 0; kk < 4; kk++) {
                const int x = (kk * 4 + lg) ^ (key & 7);
                bf16x8 kf = *(const bf16x8*)&Ks[key * 128 + x * 8];
                sc[0][n] = __builtin_amdgcn_mfma_f32_16x16x32_bf16(kf, qf[0][kk], sc[0][n], 0, 0, 0);
                sc[1][n] = __builtin_amdgcn_mfma_f32_16x16x32_bf16(kf, qf[1][kk], sc[1][n], 0, 0, 0);
            }
        }
        __builtin_amdgcn_s_setprio(0);

        // ---- online softmax per q-row (lane-local row = l15, per m) ----
        float e_bc[2][4];
#pragma unroll
        for (int m = 0; m < 2; m++) {
            float sv[4][4];
#pragma unroll
            for (int n = 0; n < 4; n++) {
                sv[n][0] = sc[m][n][0] * SCALE + mv[m][n].x;
                sv[n][1] = sc[m][n][1] * SCALE + mv[m][n].y;
                sv[n][2] = sc[m][n][2] * SCALE + mv[m][n].z;
                sv[n][3] = sc[m][n][3] * SCALE + mv[m][n].w;
            }
            float loc = sv[0][0];
#pragma unroll
            for (int n = 0; n < 4; n++)
#pragma unroll
                for (int r = 0; r < 4; r++) loc = fmaxf(loc, sv[n][r]);
            loc = fmaxf(loc, __shfl_xor(loc, 16));
            loc = fmaxf(loc, __shfl_xor(loc, 32));
            float mnew = fmaxf(mrun[m], loc);
            float esc = __expf(mrun[m] - mnew);
            mrun[m] = mnew;
            float ls = 0.f;
            const int prow = m * 16 + l15;
#pragma unroll
            for (int n = 0; n < 4; n++) {
                float p0 = __expf(sv[n][0] - mnew), p1 = __expf(sv[n][1] - mnew);
                float p2 = __expf(sv[n][2] - mnew), p3 = __expf(sv[n][3] - mnew);
                ls += (p0 + p1) + (p2 + p3);
                union { unsigned u[2]; u16x4 v; } pk;
                pk.u[0] = cvtpk(p0, p1);
                pk.u[1] = cvtpk(p2, p3);
                *(u16x4*)((char*)Pw + prow * 128 + ((n * 32 + lg * 8) ^ psw)) = pk.v;
            }
            ls += __shfl_xor(ls, 16);
            ls += __shfl_xor(ls, 32);
            lrun[m] = lrun[m] * esc + ls;
#pragma unroll
            for (int r = 0; r < 4; r++) e_bc[m][r] = __shfl(esc, lg * 4 + r);
        }

        // ---- rescale ctx ----
#pragma unroll
        for (int m = 0; m < 2; m++)
#pragma unroll
            for (int vn = 0; vn < 8; vn++)
#pragma unroll
                for (int r = 0; r < 4; r++) octx[m][vn][r] *= e_bc[m][r];

        // compiler memory fence: P stores must not be reordered past PV loads
        asm volatile("" ::: "memory");

        // ---- PV ----
        bf16x8 paf[2][2];
#pragma unroll
        for (int m = 0; m < 2; m++) {
            const int prow = m * 16 + l15;
#pragma unroll
            for (int kk = 0; kk < 2; kk++)
                paf[m][kk] = *(const bf16x8*)((char*)Pw + prow * 128
                                              + ((kk * 64 + lg * 16) ^ psw));
        }
        __builtin_amdgcn_s_setprio(1);
#pragma unroll
        for (int vn = 0; vn < 8; vn++) {
            const int d = vn * 16 + l15;
#pragma unroll
            for (int kk = 0; kk < 2; kk++) {
                const int x = (kk * 4 + lg) ^ (d & 7);
                bf16x8 vf = *(const bf16x8*)&Vs[d * 64 + x * 8];
                octx[0][vn] = __builtin_amdgcn_mfma_f32_16x16x32_bf16(paf[0][kk], vf, octx[0][vn], 0, 0, 0);
                octx[1][vn] = __builtin_amdgcn_mfma_f32_16x16x32_bf16(paf[1][kk], vf, octx[1][vn], 0, 0, 0);
            }
        }
        __builtin_amdgcn_s_setprio(0);
    }

    // ---- normalize + write ----
#pragma unroll
    for (int m = 0; m < 2; m++) {
        float inv[4];
#pragma unroll
        for (int r = 0; r < 4; r++) inv[r] = 1.0f / __shfl(lrun[m], lg * 4 + r);
#pragma unroll
        for (int vn = 0; vn < 8; vn++)
#pragma unroll
            for (int r = 0; r < 4; r++)
                ctxb[(base + q0 + m * 16 + lg * 4 + r) * 2048 + h * 128 + vn * 16 + l15]
                    = f2bf(octx[m][vn][r] * inv[r]);
    }
}

// ---------------------------------------------------------------------------
extern "C" void kernel_launch(void* const* d_in, const int* in_sizes, int n_in,
                              void* d_out, int out_size, void* d_ws, size_t ws_size,
                              hipStream_t stream)
{
    const float* hidden = (const float*)d_in[0];
    const float* mask   = (const float*)d_in[1];
    const float* W_down = (const float*)d_in[2];
    const float* W_up   = (const float*)d_in[3];
    const float* W_q    = (const float*)d_in[4];
    const float* W_o    = (const float*)d_in[5];
    float* out = (float*)d_out;

    unsigned short* p = (unsigned short*)d_ws;
    unsigned short* hb      = p; p += (size_t)MTOT * 2048;     // bf16 hidden
    unsigned short* qkd     = p; p += (size_t)MTOT * QKD_LD;   // kv_down(640) | q(2048)
    unsigned short* kvu_b   = p; p += (size_t)MTOT * 3072;
    unsigned short* vTb     = p; p += (size_t)BATCH * HEADS * 128 * S_LEN;
    unsigned short* ctxb    = p; p += (size_t)MTOT * 2048;
    unsigned short* Wt_cat  = p; p += (size_t)QKD_LD * 2048;   // W_down^T (640) | W_q^T (2048)
    unsigned short* Wt_up   = p; p += (size_t)3072 * 512;
    unsigned short* Wt_o    = p; p += (size_t)2048 * 2048;

    dim3 blk(256);
    cast_bf16<<<dim3(MTOT * 2048 / (256 * 8)), blk, 0, stream>>>(hidden, hb);
    tc_w<<<dim3(10, 32), blk, 0, stream>>>(W_down, 576, 2048, Wt_cat);
    tc_w<<<dim3(32, 32), blk, 0, stream>>>(W_q, 2048, 2048, Wt_cat + (size_t)640 * 2048);
    tc_w<<<dim3(48, 8),  blk, 0, stream>>>(W_up, 3072, 512, Wt_up);
    tc_w<<<dim3(32, 32), blk, 0, stream>>>(W_o, 2048, 2048, Wt_o);

    // fused (kv_down | q) = hb @ Wt_cat^T
    gemm_bf16<true><<<dim3(QKD_LD / 128, 32), blk, 0, stream>>>(
        hb, 2048, 2048, Wt_cat, qkd, QKD_LD, QKD_LD);
    // kv = kv_compressed @ W_up  (A = qkd cols 0..511, lda=2688)
    gemm_bf16<true><<<dim3(24, 32), blk, 0, stream>>>(
        qkd, QKD_LD, 512, Wt_up, kvu_b, 3072, 3072);

    transpose_v<<<dim3(S_LEN / 64, 2 * HEADS, BATCH), blk, 0, stream>>>(kvu_b, vTb);

    mla_attn_mfma<<<dim3(S_LEN / 128, HEADS, BATCH), blk, 0, stream>>>(
        qkd, kvu_b, vTb, mask, ctxb);

    gemm_bf16<false><<<dim3(16, 32), blk, 0, stream>>>(
        ctxb, 2048, 2048, Wt_o, out, 2048, 2048);
}